// Round 5
// baseline (43.446 us; speedup 1.0000x reference)
//
#include <hip/hip_runtime.h>
#include <math.h>

typedef __attribute__((ext_vector_type(8))) short short8;
typedef __attribute__((ext_vector_type(4))) float f32x4;

#define NPX 8192
#define NPATCH 8192
#define SPLITS 32
#define TILES_PER_SPLIT 16   // 256 patches per split
#define WPB 4                // waves per block
#define PXB 32               // pixel-blocks (8192 / (WPB*64))

__device__ __forceinline__ float fexp2(float x) {
#if __has_builtin(__builtin_amdgcn_exp2f)
    return __builtin_amdgcn_exp2f(x);
#else
    return exp2f(x);
#endif
}

__device__ __forceinline__ unsigned short f2bf(float f) {
    unsigned u = __float_as_uint(f);
    u = u + 0x7FFFu + ((u >> 16) & 1u);
    return (unsigned short)(u >> 16);
}
__device__ __forceinline__ float bf2f(unsigned short h) {
    return __uint_as_float(((unsigned)h) << 16);
}

// ---- fused: build A-records (LDS) + B-fragments (reg) + MFMA online softmax
__global__ void __launch_bounds__(256) main_fused(
        const float* __restrict__ x,
        const float* __restrict__ patches,
        const float* __restrict__ t,
        float* __restrict__ pm, float* __restrict__ ps,
        float* __restrict__ pc0, float* __restrict__ pc1, float* __restrict__ pc2) {
    __shared__ short8 sAh[TILES_PER_SPLIT * 64];   // 16 KB
    __shared__ short8 sAl[TILES_PER_SPLIT * 64];   // 16 KB
    __shared__ float  sCent[TILES_PER_SPLIT * 48]; // 3 KB
    const int tid = threadIdx.x;
    const int lane = tid & 63, wid = tid >> 6;
    const int split = blockIdx.x, pxb = blockIdx.y;

    const float bt2 = t[0];
    const float at = sqrtf(1.0f - bt2);
    const float L2E = 1.4426950408889634f;
    const float A2 = at * L2E / bt2;                 // logit slope, log2 units

    // ---- A-build: thread i owns patch split*256+i ----
    {
        const int p = split * 256 + tid;
        const float* src = patches + p * 27;
        float v[27]; float pn = 0.f;
#pragma unroll
        for (int k = 0; k < 27; k++) { v[k] = src[k]; pn += v[k] * v[k]; }
        const float B2 = -at * at * pn * L2E / (2.0f * bt2);
        float sv[28];
#pragma unroll
        for (int k = 0; k < 27; k++) sv[k] = A2 * v[k];
        sv[27] = B2;
        const int j = tid >> 4, pi = tid & 15;
#pragma unroll
        for (int c = 0; c < 4; c++) {
            short8 H, L;
#pragma unroll
            for (int i = 0; i < 8; i++) {
                int k = c * 8 + i;
                unsigned short hb = 0, lb = 0;
                if (k < 28) { hb = f2bf(sv[k]); lb = f2bf(sv[k] - bf2f(hb)); }
                H[i] = (short)hb; L[i] = (short)lb;
            }
            sAh[j * 64 + c * 16 + pi] = H;
            sAl[j * 64 + c * 16 + pi] = L;
        }
        sCent[j * 48 + 0  + pi] = v[4];
        sCent[j * 48 + 16 + pi] = v[13];
        sCent[j * 48 + 32 + pi] = v[22];
    }

    // ---- B-build: wave owns 64 pixels (4 groups of 16); fragments in regs ----
    const int pxg0 = (pxb * WPB + wid) * 4;
    const int c = lane >> 4;                        // k-chunk of this lane
    short8 bh[4], bl[4];
#pragma unroll
    for (int j = 0; j < 4; j++) {
        const int px = (pxg0 + j) * 16 + (lane & 15);
        const int b = px >> 10, rem = px & 1023, h = rem >> 5, w = rem & 31;
        short8 H, L;
#pragma unroll
        for (int i = 0; i < 8; i++) {
            int k = c * 8 + i;
            float val = 0.0f;
            if (k < 27) {
                int c3 = k / 9, r9 = k - 9 * c3;
                int dr = r9 / 3, dc = r9 - 3 * dr;
                int hh = h + dr - 1, ww = w + dc - 1;
                if ((unsigned)hh < 32u && (unsigned)ww < 32u)
                    val = x[b * 3072 + c3 * 1024 + hh * 32 + ww];
            } else if (k == 27) {
                val = 1.0f;
            }
            unsigned short hb = f2bf(val);
            unsigned short lb = f2bf(val - bf2f(hb));
            H[i] = (short)hb; L[i] = (short)lb;
        }
        bh[j] = H; bl[j] = L;
    }
    __syncthreads();

    float m[4], s[4], a0[4], a1[4], a2[4];
#pragma unroll
    for (int j = 0; j < 4; j++) { m[j] = -1e30f; s[j] = 0.f; a0[j] = 0.f; a1[j] = 0.f; a2[j] = 0.f; }

    const int g = lane >> 4;
    for (int tt = 0; tt < TILES_PER_SPLIT; tt++) {
        short8 ah = sAh[tt * 64 + lane];
        short8 al = sAl[tt * 64 + lane];
        const float4 c0 = ((const float4*)sCent)[tt * 12 + 0 + g];
        const float4 c1 = ((const float4*)sCent)[tt * 12 + 4 + g];
        const float4 c2 = ((const float4*)sCent)[tt * 12 + 8 + g];
#pragma unroll
        for (int jj = 0; jj < 2; jj++) {
            const int jA = 2 * jj, jB = 2 * jj + 1;
            f32x4 dA = {0.f, 0.f, 0.f, 0.f};
            dA = __builtin_amdgcn_mfma_f32_16x16x32_bf16(al, bh[jA], dA, 0, 0, 0);
            dA = __builtin_amdgcn_mfma_f32_16x16x32_bf16(ah, bl[jA], dA, 0, 0, 0);
            dA = __builtin_amdgcn_mfma_f32_16x16x32_bf16(ah, bh[jA], dA, 0, 0, 0);
            f32x4 dB = {0.f, 0.f, 0.f, 0.f};
            dB = __builtin_amdgcn_mfma_f32_16x16x32_bf16(al, bh[jB], dB, 0, 0, 0);
            dB = __builtin_amdgcn_mfma_f32_16x16x32_bf16(ah, bl[jB], dB, 0, 0, 0);
            dB = __builtin_amdgcn_mfma_f32_16x16x32_bf16(ah, bh[jB], dB, 0, 0, 0);

            float tmA = fmaxf(fmaxf(dA.x, dA.y), fmaxf(dA.z, dA.w));
            if (__any(tmA > m[jA] - 30.0f)) {
                if (__any(tmA > m[jA] + 8.0f)) {
                    float mn = fmaxf(m[jA], tmA);
                    float sc = fexp2(m[jA] - mn);
                    s[jA] *= sc; a0[jA] *= sc; a1[jA] *= sc; a2[jA] *= sc; m[jA] = mn;
                }
                float e0 = fexp2(dA.x - m[jA]);
                float e1 = fexp2(dA.y - m[jA]);
                float e2 = fexp2(dA.z - m[jA]);
                float e3 = fexp2(dA.w - m[jA]);
                s[jA] += (e0 + e1) + (e2 + e3);
                a0[jA] = fmaf(e0, c0.x, fmaf(e1, c0.y, fmaf(e2, c0.z, fmaf(e3, c0.w, a0[jA]))));
                a1[jA] = fmaf(e0, c1.x, fmaf(e1, c1.y, fmaf(e2, c1.z, fmaf(e3, c1.w, a1[jA]))));
                a2[jA] = fmaf(e0, c2.x, fmaf(e1, c2.y, fmaf(e2, c2.z, fmaf(e3, c2.w, a2[jA]))));
            }
            float tmB = fmaxf(fmaxf(dB.x, dB.y), fmaxf(dB.z, dB.w));
            if (__any(tmB > m[jB] - 30.0f)) {
                if (__any(tmB > m[jB] + 8.0f)) {
                    float mn = fmaxf(m[jB], tmB);
                    float sc = fexp2(m[jB] - mn);
                    s[jB] *= sc; a0[jB] *= sc; a1[jB] *= sc; a2[jB] *= sc; m[jB] = mn;
                }
                float e0 = fexp2(dB.x - m[jB]);
                float e1 = fexp2(dB.y - m[jB]);
                float e2 = fexp2(dB.z - m[jB]);
                float e3 = fexp2(dB.w - m[jB]);
                s[jB] += (e0 + e1) + (e2 + e3);
                a0[jB] = fmaf(e0, c0.x, fmaf(e1, c0.y, fmaf(e2, c0.z, fmaf(e3, c0.w, a0[jB]))));
                a1[jB] = fmaf(e0, c1.x, fmaf(e1, c1.y, fmaf(e2, c1.z, fmaf(e3, c1.w, a1[jB]))));
                a2[jB] = fmaf(e0, c2.x, fmaf(e1, c2.y, fmaf(e2, c2.z, fmaf(e3, c2.w, a2[jB]))));
            }
        }
    }

    // merge the 4 lane-groups (patch sub-rows) sharing each pixel
#pragma unroll
    for (int j = 0; j < 4; j++) {
#pragma unroll
        for (int off = 16; off <= 32; off <<= 1) {
            float mo = __shfl_xor(m[j], off);
            float so = __shfl_xor(s[j], off);
            float b0 = __shfl_xor(a0[j], off);
            float b1 = __shfl_xor(a1[j], off);
            float b2 = __shfl_xor(a2[j], off);
            float mn = fmaxf(m[j], mo);
            float w1 = fexp2(m[j] - mn), w2 = fexp2(mo - mn);
            s[j]  = s[j]  * w1 + so * w2;
            a0[j] = a0[j] * w1 + b0 * w2;
            a1[j] = a1[j] * w1 + b1 * w2;
            a2[j] = a2[j] * w1 + b2 * w2;
            m[j] = mn;
        }
    }
    float M  = (g == 0) ? m[0]  : (g == 1) ? m[1]  : (g == 2) ? m[2]  : m[3];
    float S  = (g == 0) ? s[0]  : (g == 1) ? s[1]  : (g == 2) ? s[2]  : s[3];
    float A0 = (g == 0) ? a0[0] : (g == 1) ? a0[1] : (g == 2) ? a0[2] : a0[3];
    float A1 = (g == 0) ? a1[0] : (g == 1) ? a1[1] : (g == 2) ? a1[2] : a1[3];
    float A2v= (g == 0) ? a2[0] : (g == 1) ? a2[1] : (g == 2) ? a2[2] : a2[3];
    int o = split * NPX + pxg0 * 16 + lane;
    pm[o] = M; ps[o] = S; pc0[o] = A0; pc1[o] = A1; pc2[o] = A2v;
}

// ---- combine partials + write output ----
__global__ void __launch_bounds__(64) combine(const float* __restrict__ x, const float* __restrict__ t,
                        const float* __restrict__ pm, const float* __restrict__ ps,
                        const float* __restrict__ pc0, const float* __restrict__ pc1,
                        const float* __restrict__ pc2, float* __restrict__ out) {
    int px = blockIdx.x * 64 + threadIdx.x;
    if (px >= NPX) return;
    float M = -1e30f, S = 0.0f, C0 = 0.0f, C1 = 0.0f, C2 = 0.0f;
#pragma unroll 8
    for (int sp = 0; sp < SPLITS; sp++) {
        int o = sp * NPX + px;
        float mi = pm[o];
        float Mn = fmaxf(M, mi);
        float al = fexp2(M - Mn);
        float be = fexp2(mi - Mn);
        S  = S  * al + ps[o]  * be;
        C0 = C0 * al + pc0[o] * be;
        C1 = C1 * al + pc1[o] * be;
        C2 = C2 * al + pc2[o] * be;
        M = Mn;
    }
    float bt2 = t[0];
    float at = sqrtf(1.0f - bt2);
    float invS = 1.0f / S;
    float ibt = 1.0f / bt2;
    int b = px >> 10, rem = px & 1023, h = rem >> 5, w = rem & 31;
    int xi = b * 3072 + h * 32 + w;
    out[xi]        = (at * C0 * invS - x[xi]) * ibt;
    out[xi + 1024] = (at * C1 * invS - x[xi + 1024]) * ibt;
    out[xi + 2048] = (at * C2 * invS - x[xi + 2048]) * ibt;
}

extern "C" void kernel_launch(void* const* d_in, const int* in_sizes, int n_in,
                              void* d_out, int out_size, void* d_ws, size_t ws_size,
                              hipStream_t stream) {
    const float* x = (const float*)d_in[0];
    const float* patches = (const float*)d_in[1];
    const float* t = (const float*)d_in[2];
    float* out = (float*)d_out;
    float* ws = (float*)d_ws;

    float* pm  = ws;                      // SPLITS*NPX floats each
    float* ps  = pm + SPLITS * NPX;
    float* pc0 = ps + SPLITS * NPX;
    float* pc1 = pc0 + SPLITS * NPX;
    float* pc2 = pc1 + SPLITS * NPX;

    hipLaunchKernelGGL(main_fused, dim3(SPLITS, PXB), dim3(WPB * 64), 0, stream,
                       x, patches, t, pm, ps, pc0, pc1, pc2);
    hipLaunchKernelGGL(combine, dim3(NPX / 64), dim3(64), 0, stream,
                       x, t, pm, ps, pc0, pc1, pc2, out);
}

// Round 7
// 42.162 us; speedup vs baseline: 1.0304x; 1.0304x over previous
//
#include <hip/hip_runtime.h>
#include <math.h>

typedef __attribute__((ext_vector_type(8))) short short8;
typedef __attribute__((ext_vector_type(4))) float f32x4;
typedef __attribute__((ext_vector_type(4))) unsigned int uint4v;

#define NPX 8192
#define NPATCH 8192
#define SPLITS 32
#define TILES 16             // 16-patch tiles per split (256 patches/split)
#define WPB 8                // waves per block (512 threads)
#define PXB 16               // pixel-blocks: 16 * 8 waves * 64 px = 8192

__device__ __forceinline__ float fexp2(float x) {
#if __has_builtin(__builtin_amdgcn_exp2f)
    return __builtin_amdgcn_exp2f(x);
#else
    return exp2f(x);
#endif
}

__device__ __forceinline__ unsigned short f2bf(float f) {
    unsigned u = __float_as_uint(f);
    u = u + 0x7FFFu + ((u >> 16) & 1u);
    return (unsigned short)(u >> 16);
}
__device__ __forceinline__ float bf2f(unsigned short h) {
    return __uint_as_float(((unsigned)h) << 16);
}

// ---- prep: A-fragments (patches, hi/lo, slot27=B2, slot28=1.0),
//            B-fragments (pixels, hi/lo, slot27=1.0, slot28=0 [m-slot]),
//            V-fragments (centers hi/lo + ones column), all MFMA-ordered.
__global__ void __launch_bounds__(256) prep(const float* __restrict__ x,
                          const float* __restrict__ patches,
                          const float* __restrict__ t,
                          float* __restrict__ gAh, float* __restrict__ gAl,
                          float* __restrict__ gBh, float* __restrict__ gBl,
                          float* __restrict__ gVh, float* __restrict__ gVl) {
    int id = blockIdx.x * 256 + threadIdx.x;
    float bt2 = t[0];
    float at = sqrtf(1.0f - bt2);
    const float L2E = 1.4426950408889634f;
    if (id < NPATCH) {
        int p = id;
        const float* src = patches + p * 27;
        float v[27]; float pn = 0.f;
#pragma unroll
        for (int k = 0; k < 27; k++) { v[k] = src[k]; pn += v[k] * v[k]; }
        float A2 = at * L2E / bt2;
        float B2 = -at * at * pn * L2E / (2.0f * bt2);
        float sv[28];
#pragma unroll
        for (int k = 0; k < 27; k++) sv[k] = A2 * v[k];
        sv[27] = B2;
        int j = p >> 4, pi = p & 15;
        short8* Ah8 = (short8*)gAh; short8* Al8 = (short8*)gAl;
#pragma unroll
        for (int c = 0; c < 4; c++) {
            short8 H, L;
#pragma unroll
            for (int i = 0; i < 8; i++) {
                int k = c * 8 + i;
                unsigned short hb = 0, lb = 0;
                if (k < 28) { hb = f2bf(sv[k]); lb = f2bf(sv[k] - bf2f(hb)); }
                else if (k == 28) { hb = 0x3F80; lb = 0; }   // 1.0 for m-injection
                H[i] = (short)hb; L[i] = (short)lb;
            }
            Ah8[j * 64 + c * 16 + pi] = H;
            Al8[j * 64 + c * 16 + pi] = L;
        }
    } else if (id < NPATCH + NPX) {
        int px = id - NPATCH;
        int b = px >> 10, rem = px & 1023, h = rem >> 5, w = rem & 31;
        float xv[28];
#pragma unroll
        for (int c3 = 0; c3 < 3; c3++)
#pragma unroll
        for (int dr = 0; dr < 3; dr++)
#pragma unroll
        for (int dc = 0; dc < 3; dc++) {
            int hh = h + dr - 1, ww = w + dc - 1;
            float val = 0.f;
            if ((unsigned)hh < 32u && (unsigned)ww < 32u)
                val = x[b * 3072 + c3 * 1024 + hh * 32 + ww];
            xv[c3 * 9 + dr * 3 + dc] = val;
        }
        xv[27] = 1.0f;
        int wv = px >> 4, pi = px & 15;
        short8* Bh8 = (short8*)gBh; short8* Bl8 = (short8*)gBl;
#pragma unroll
        for (int c = 0; c < 4; c++) {
            short8 H, L;
#pragma unroll
            for (int i = 0; i < 8; i++) {
                int k = c * 8 + i;
                unsigned short hb = 0, lb = 0;
                if (k < 28) { hb = f2bf(xv[k]); lb = f2bf(xv[k] - bf2f(hb)); }
                H[i] = (short)hb; L[i] = (short)lb;
            }
            Bh8[wv * 64 + c * 16 + pi] = H;
            Bl8[wv * 64 + c * 16 + pi] = L;
        }
    } else {
        // V-fragments: one thread per (tile, lane). B[k=8g+i][col] = i<4 ? V[tile*16+4g+i][col] : 0
        int vid = id - (NPATCH + NPX);          // 0 .. 512*64-1
        int tile = vid >> 6, lane = vid & 63;
        int g = (lane >> 4) & 3, col = lane & 15;
        short8 H, L;
#pragma unroll
        for (int i = 0; i < 8; i++) {
            unsigned short hb = 0, lb = 0;
            if (i < 4 && col < 4) {
                float val;
                if (col == 3) val = 1.0f;       // ones column -> S
                else {
                    int p = tile * 16 + 4 * g + i;
                    val = patches[p * 27 + (col == 0 ? 4 : col == 1 ? 13 : 22)];
                }
                hb = f2bf(val); lb = f2bf(val - bf2f(hb));
            }
            H[i] = (short)hb; L[i] = (short)lb;
        }
        ((short8*)gVh)[vid] = H;
        ((short8*)gVl)[vid] = L;
    }
}

// ---- main: pass1 approx-max, inject -m into k-slot 28, pass2 exp + PV-MFMA
__global__ void __launch_bounds__(512) main_mfma(
        const float* __restrict__ gAh, const float* __restrict__ gAl,
        const float* __restrict__ gBh, const float* __restrict__ gBl,
        const float* __restrict__ gVh, const float* __restrict__ gVl,
        float* __restrict__ pm, float* __restrict__ ps,
        float* __restrict__ pc0, float* __restrict__ pc1, float* __restrict__ pc2) {
    __shared__ short8 sAh[TILES * 64];   // 16 KB each, 64 KB total
    __shared__ short8 sAl[TILES * 64];
    __shared__ short8 sVh[TILES * 64];
    __shared__ short8 sVl[TILES * 64];
    const int tid = threadIdx.x;
    const int lane = tid & 63, wid = tid >> 6;
    const int split = blockIdx.x, pxb = blockIdx.y;
    const int tb = split * TILES;

    // stage A and V fragment records (coalesced float4)
    {
        const float4* s0 = (const float4*)gAh + tb * 64;
        const float4* s1 = (const float4*)gAl + tb * 64;
        const float4* s2 = (const float4*)gVh + tb * 64;
        const float4* s3 = (const float4*)gVl + tb * 64;
        float4* d0 = (float4*)sAh; float4* d1 = (float4*)sAl;
        float4* d2 = (float4*)sVh; float4* d3 = (float4*)sVl;
#pragma unroll
        for (int i = 0; i < 2; i++) {
            d0[tid + i * 512] = s0[tid + i * 512];
            d1[tid + i * 512] = s1[tid + i * 512];
            d2[tid + i * 512] = s2[tid + i * 512];
            d3[tid + i * 512] = s3[tid + i * 512];
        }
    }

    // pixel fragments: 4 groups of 16 pixels per wave
    const int pxg0 = pxb * WPB + wid;            // 0..127
    short8 bh[4], bl[4];
#pragma unroll
    for (int j = 0; j < 4; j++) {
        bh[j] = ((const short8*)gBh)[(pxg0 * 4 + j) * 64 + lane];
        bl[j] = ((const short8*)gBl)[(pxg0 * 4 + j) * 64 + lane];
    }
    __syncthreads();

    const f32x4 z4 = {0.f, 0.f, 0.f, 0.f};

    // ---- pass 1: approximate logits (hi*hi only), per-pixel max ----
    float rmax[4];
#pragma unroll
    for (int j = 0; j < 4; j++) rmax[j] = -3e38f;
    for (int tt = 0; tt < TILES; tt++) {
        short8 ah = sAh[tt * 64 + lane];
#pragma unroll
        for (int j = 0; j < 4; j++) {
            f32x4 d = __builtin_amdgcn_mfma_f32_16x16x32_bf16(ah, bh[j], z4, 0, 0, 0);
            rmax[j] = fmaxf(rmax[j], fmaxf(fmaxf(d.x, d.y), fmaxf(d.z, d.w)));
        }
    }
    float mval[4];
#pragma unroll
    for (int j = 0; j < 4; j++) {
        float r = fmaxf(rmax[j], __shfl_xor(rmax[j], 16));
        r = fmaxf(r, __shfl_xor(r, 32));                 // per-pixel max over all sub-rows
        unsigned short mh = f2bf(-r);                    // -m̂ in bf16
        mval[j] = -bf2f(mh);                             // exact m̂ applied in pass 2
        // inject -m̂ into k-slot 28 (element 4 of the c==3 lane chunk)
        bh[j][4] = ((lane >> 4) == 3) ? (short)mh : bh[j][4];
    }

    // ---- pass 2: full logits (-m̂ folded in), exp2 (clamped), PV via MFMA ----
    f32x4 O[4] = {z4, z4, z4, z4};
    for (int tt = 0; tt < TILES; tt++) {
        short8 ah = sAh[tt * 64 + lane];
        short8 al = sAl[tt * 64 + lane];
        short8 vh = sVh[tt * 64 + lane];
        short8 vl = sVl[tt * 64 + lane];
#pragma unroll
        for (int j = 0; j < 4; j++) {
            f32x4 d = __builtin_amdgcn_mfma_f32_16x16x32_bf16(al, bh[j], z4, 0, 0, 0);
            d = __builtin_amdgcn_mfma_f32_16x16x32_bf16(ah, bl[j], d, 0, 0, 0);
            d = __builtin_amdgcn_mfma_f32_16x16x32_bf16(ah, bh[j], d, 0, 0, 0);
            float e0 = fexp2(fminf(d.x, 30.0f));
            float e1 = fexp2(fminf(d.y, 30.0f));
            float e2 = fexp2(fminf(d.z, 30.0f));
            float e3 = fexp2(fminf(d.w, 30.0f));
            uint4v pu;
            pu.x = ((unsigned)f2bf(e1) << 16) | (unsigned)f2bf(e0);
            pu.y = ((unsigned)f2bf(e3) << 16) | (unsigned)f2bf(e2);
            pu.z = 0u; pu.w = 0u;
            short8 pa = __builtin_bit_cast(short8, pu);
            O[j] = __builtin_amdgcn_mfma_f32_16x16x32_bf16(pa, vh, O[j], 0, 0, 0);
            O[j] = __builtin_amdgcn_mfma_f32_16x16x32_bf16(pa, vl, O[j], 0, 0, 0);
        }
    }

    // ---- write partials ----
    if (lane < 16) {
#pragma unroll
        for (int j = 0; j < 4; j++)
            pm[split * NPX + (pxg0 * 4 + j) * 16 + lane] = mval[j];
    }
    // O: lane holds channel ch=lane&15, pixels 4*(lane>>4)+reg
    const int ch = lane & 15, rg = lane >> 4;
    if (ch < 4) {
        float* dst = (ch == 0) ? pc0 : (ch == 1) ? pc1 : (ch == 2) ? pc2 : ps;
#pragma unroll
        for (int j = 0; j < 4; j++) {
            int base = split * NPX + (pxg0 * 4 + j) * 16 + 4 * rg;
            dst[base + 0] = O[j].x;
            dst[base + 1] = O[j].y;
            dst[base + 2] = O[j].z;
            dst[base + 3] = O[j].w;
        }
    }
}

// ---- combine partials + write output ----
__global__ void __launch_bounds__(64) combine(const float* __restrict__ x, const float* __restrict__ t,
                        const float* __restrict__ pm, const float* __restrict__ ps,
                        const float* __restrict__ pc0, const float* __restrict__ pc1,
                        const float* __restrict__ pc2, float* __restrict__ out) {
    int px = blockIdx.x * 64 + threadIdx.x;
    if (px >= NPX) return;
    float M = -1e30f, S = 0.0f, C0 = 0.0f, C1 = 0.0f, C2 = 0.0f;
#pragma unroll 8
    for (int sp = 0; sp < SPLITS; sp++) {
        int o = sp * NPX + px;
        float mi = pm[o];
        float Mn = fmaxf(M, mi);
        float al = fexp2(M - Mn);
        float be = fexp2(mi - Mn);
        S  = S  * al + ps[o]  * be;
        C0 = C0 * al + pc0[o] * be;
        C1 = C1 * al + pc1[o] * be;
        C2 = C2 * al + pc2[o] * be;
        M = Mn;
    }
    float bt2 = t[0];
    float at = sqrtf(1.0f - bt2);
    float invS = 1.0f / fmaxf(S, 1e-37f);
    float ibt = 1.0f / bt2;
    int b = px >> 10, rem = px & 1023, h = rem >> 5, w = rem & 31;
    int xi = b * 3072 + h * 32 + w;
    out[xi]        = (at * C0 * invS - x[xi]) * ibt;
    out[xi + 1024] = (at * C1 * invS - x[xi + 1024]) * ibt;
    out[xi + 2048] = (at * C2 * invS - x[xi + 2048]) * ibt;
}

extern "C" void kernel_launch(void* const* d_in, const int* in_sizes, int n_in,
                              void* d_out, int out_size, void* d_ws, size_t ws_size,
                              hipStream_t stream) {
    const float* x = (const float*)d_in[0];
    const float* patches = (const float*)d_in[1];
    const float* t = (const float*)d_in[2];
    float* out = (float*)d_out;
    float* ws = (float*)d_ws;

    float* gAh = ws;                      // 131072 floats each (512 tiles * 64 recs * 16B)
    float* gAl = ws + 131072;
    float* gBh = ws + 262144;
    float* gBl = ws + 393216;
    float* gVh = ws + 524288;
    float* gVl = ws + 655360;
    float* pm  = ws + 786432;             // 32*8192 floats each -> total 8.0 MiB
    float* ps  = pm + SPLITS * NPX;
    float* pc0 = ps + SPLITS * NPX;
    float* pc1 = pc0 + SPLITS * NPX;
    float* pc2 = pc1 + SPLITS * NPX;

    hipLaunchKernelGGL(prep, dim3(192), dim3(256), 0, stream,
                       x, patches, t, gAh, gAl, gBh, gBl, gVh, gVl);
    hipLaunchKernelGGL(main_mfma, dim3(SPLITS, PXB), dim3(WPB * 64), 0, stream,
                       gAh, gAl, gBh, gBl, gVh, gVl, pm, ps, pc0, pc1, pc2);
    hipLaunchKernelGGL(combine, dim3(NPX / 64), dim3(64), 0, stream,
                       x, t, pm, ps, pc0, pc1, pc2, out);
}

// Round 9
// 41.430 us; speedup vs baseline: 1.0487x; 1.0177x over previous
//
#include <hip/hip_runtime.h>
#include <math.h>

typedef __attribute__((ext_vector_type(8))) short short8;
typedef __attribute__((ext_vector_type(4))) float f32x4;
typedef __attribute__((ext_vector_type(4))) unsigned int uint4v;

#define NPX 8192
#define NPATCH 8192
#define SPLITS 32
#define TILES 16             // 16-patch tiles per split (256 patches/split)
#define WPB 8                // waves per block (512 threads)
#define PXB 32               // pixel-blocks: 32 blocks * 8 waves * 32 px = 8192

__device__ __forceinline__ float fexp2(float x) {
#if __has_builtin(__builtin_amdgcn_exp2f)
    return __builtin_amdgcn_exp2f(x);
#else
    return exp2f(x);
#endif
}

__device__ __forceinline__ unsigned short f2bf(float f) {
    unsigned u = __float_as_uint(f);
    u = u + 0x7FFFu + ((u >> 16) & 1u);
    return (unsigned short)(u >> 16);
}
__device__ __forceinline__ float bf2f(unsigned short h) {
    return __uint_as_float(((unsigned)h) << 16);
}

// ---- prep: A-fragments (patches, hi/lo, slot27=B2, slot28=1.0),
//            B-fragments (pixels, hi/lo, slot27=1.0, slot28=0 [m-slot]),
//            V-fragments (centers: hi in k-elems 0..3, lo in 4..7), MFMA-ordered.
__global__ void __launch_bounds__(256) prep(const float* __restrict__ x,
                          const float* __restrict__ patches,
                          const float* __restrict__ t,
                          float* __restrict__ gAh, float* __restrict__ gAl,
                          float* __restrict__ gBh, float* __restrict__ gBl,
                          float* __restrict__ gVh) {
    int id = blockIdx.x * 256 + threadIdx.x;
    float bt2 = t[0];
    float at = sqrtf(1.0f - bt2);
    const float L2E = 1.4426950408889634f;
    if (id < NPATCH) {
        int p = id;
        const float* src = patches + p * 27;
        float v[27]; float pn = 0.f;
#pragma unroll
        for (int k = 0; k < 27; k++) { v[k] = src[k]; pn += v[k] * v[k]; }
        float A2 = at * L2E / bt2;
        float B2 = -at * at * pn * L2E / (2.0f * bt2);
        float sv[28];
#pragma unroll
        for (int k = 0; k < 27; k++) sv[k] = A2 * v[k];
        sv[27] = B2;
        int j = p >> 4, pi = p & 15;
        short8* Ah8 = (short8*)gAh; short8* Al8 = (short8*)gAl;
#pragma unroll
        for (int c = 0; c < 4; c++) {
            short8 H, L;
#pragma unroll
            for (int i = 0; i < 8; i++) {
                int k = c * 8 + i;
                unsigned short hb = 0, lb = 0;
                if (k < 28) { hb = f2bf(sv[k]); lb = f2bf(sv[k] - bf2f(hb)); }
                else if (k == 28) { hb = 0x3F80; lb = 0; }   // 1.0 for m-injection
                H[i] = (short)hb; L[i] = (short)lb;
            }
            Ah8[j * 64 + c * 16 + pi] = H;
            Al8[j * 64 + c * 16 + pi] = L;
        }
    } else if (id < NPATCH + NPX) {
        int px = id - NPATCH;
        int b = px >> 10, rem = px & 1023, h = rem >> 5, w = rem & 31;
        float xv[28];
#pragma unroll
        for (int c3 = 0; c3 < 3; c3++)
#pragma unroll
        for (int dr = 0; dr < 3; dr++)
#pragma unroll
        for (int dc = 0; dc < 3; dc++) {
            int hh = h + dr - 1, ww = w + dc - 1;
            float val = 0.f;
            if ((unsigned)hh < 32u && (unsigned)ww < 32u)
                val = x[b * 3072 + c3 * 1024 + hh * 32 + ww];
            xv[c3 * 9 + dr * 3 + dc] = val;
        }
        xv[27] = 1.0f;
        int wv = px >> 4, pi = px & 15;
        short8* Bh8 = (short8*)gBh; short8* Bl8 = (short8*)gBl;
#pragma unroll
        for (int c = 0; c < 4; c++) {
            short8 H, L;
#pragma unroll
            for (int i = 0; i < 8; i++) {
                int k = c * 8 + i;
                unsigned short hb = 0, lb = 0;
                if (k < 28) { hb = f2bf(xv[k]); lb = f2bf(xv[k] - bf2f(hb)); }
                H[i] = (short)hb; L[i] = (short)lb;
            }
            Bh8[wv * 64 + c * 16 + pi] = H;
            Bl8[wv * 64 + c * 16 + pi] = L;
        }
    } else {
        // V-fragments: elems 0..3 = center hi (patches 4g..4g+3), elems 4..7 = lo.
        // cols 0..2 = channel centers, col 3 = ones (S column). Other cols zero.
        int vid = id - (NPATCH + NPX);          // 0 .. 512*64-1
        int tile = vid >> 6, lane = vid & 63;
        int g = (lane >> 4) & 3, col = lane & 15;
        short8 H;
#pragma unroll
        for (int i = 0; i < 8; i++) {
            unsigned short bb = 0;
            if (col < 4) {
                int ii = i & 3;
                float val;
                if (col == 3) val = 1.0f;       // ones column -> S
                else {
                    int p = tile * 16 + 4 * g + ii;
                    val = patches[p * 27 + (col == 0 ? 4 : col == 1 ? 13 : 22)];
                }
                unsigned short hb = f2bf(val);
                bb = (i < 4) ? hb : f2bf(val - bf2f(hb));   // hi then lo
            }
            H[i] = (short)bb;
        }
        ((short8*)gVh)[vid] = H;
    }
}

// ---- main: pass1 approx-max, inject -m into k-slot 28, pass2 exp + PV-MFMA
__global__ void __launch_bounds__(512) main_mfma(
        const float* __restrict__ gAh, const float* __restrict__ gAl,
        const float* __restrict__ gBh, const float* __restrict__ gBl,
        const float* __restrict__ gVh,
        float* __restrict__ pm, float* __restrict__ ps,
        float* __restrict__ pc0, float* __restrict__ pc1, float* __restrict__ pc2) {
    __shared__ short8 sAh[TILES * 64];   // 16 KB each, 48 KB total -> 3 blocks/CU
    __shared__ short8 sAl[TILES * 64];
    __shared__ short8 sVh[TILES * 64];
    const int tid = threadIdx.x;
    const int lane = tid & 63, wid = tid >> 6;
    const int split = blockIdx.x, pxb = blockIdx.y;
    const int tb = split * TILES;

    // stage A-hi, A-lo, V fragment records (coalesced float4)
    {
        const float4* s0 = (const float4*)gAh + tb * 64;
        const float4* s1 = (const float4*)gAl + tb * 64;
        const float4* s2 = (const float4*)gVh + tb * 64;
        float4* d0 = (float4*)sAh; float4* d1 = (float4*)sAl; float4* d2 = (float4*)sVh;
#pragma unroll
        for (int i = 0; i < 2; i++) {
            d0[tid + i * 512] = s0[tid + i * 512];
            d1[tid + i * 512] = s1[tid + i * 512];
            d2[tid + i * 512] = s2[tid + i * 512];
        }
    }

    // pixel fragments: 2 groups of 16 pixels per wave (32 px/wave)
    const int pxg = pxb * WPB + wid;             // 0..255
    short8 bh[2], bl[2];
#pragma unroll
    for (int j = 0; j < 2; j++) {
        bh[j] = ((const short8*)gBh)[(pxg * 2 + j) * 64 + lane];
        bl[j] = ((const short8*)gBl)[(pxg * 2 + j) * 64 + lane];
    }
    __syncthreads();

    const f32x4 z4 = {0.f, 0.f, 0.f, 0.f};

    // ---- pass 1: approximate logits (hi*hi only), per-pixel max ----
    // register double-buffer the tile fragment to hide ds_read latency
    float rmax[2] = {-3e38f, -3e38f};
    {
        short8 ah = sAh[lane];
#pragma unroll 4
        for (int tt = 0; tt < TILES; tt++) {
            short8 ah_n = sAh[((tt + 1) & (TILES - 1)) * 64 + lane];
#pragma unroll
            for (int j = 0; j < 2; j++) {
                f32x4 d = __builtin_amdgcn_mfma_f32_16x16x32_bf16(ah, bh[j], z4, 0, 0, 0);
                rmax[j] = fmaxf(rmax[j], fmaxf(fmaxf(d.x, d.y), fmaxf(d.z, d.w)));
            }
            ah = ah_n;
        }
    }
    float mval[2];
#pragma unroll
    for (int j = 0; j < 2; j++) {
        float r = fmaxf(rmax[j], __shfl_xor(rmax[j], 16));
        r = fmaxf(r, __shfl_xor(r, 32));                 // per-pixel max over all sub-rows
        unsigned short mh = f2bf(-r);                    // -m̂ in bf16
        mval[j] = -bf2f(mh);                             // exact m̂ applied in pass 2
        // inject -m̂ into k-slot 28 (element 4 of the c==3 lane chunk)
        bh[j][4] = ((lane >> 4) == 3) ? (short)mh : bh[j][4];
    }

    // ---- pass 2: full logits (-m̂ folded in), exp2 (clamped), PV via MFMA ----
    f32x4 O[2] = {z4, z4};
    {
        short8 ah = sAh[lane], al = sAl[lane], vh = sVh[lane];
#pragma unroll 4
        for (int tt = 0; tt < TILES; tt++) {
            const int tn = ((tt + 1) & (TILES - 1)) * 64 + lane;
            short8 ah_n = sAh[tn];
            short8 al_n = sAl[tn];
            short8 vh_n = sVh[tn];
#pragma unroll
            for (int j = 0; j < 2; j++) {
                f32x4 d = __builtin_amdgcn_mfma_f32_16x16x32_bf16(al, bh[j], z4, 0, 0, 0);
                d = __builtin_amdgcn_mfma_f32_16x16x32_bf16(ah, bl[j], d, 0, 0, 0);
                d = __builtin_amdgcn_mfma_f32_16x16x32_bf16(ah, bh[j], d, 0, 0, 0);
                float e0 = fexp2(fminf(d.x, 30.0f));
                float e1 = fexp2(fminf(d.y, 30.0f));
                float e2 = fexp2(fminf(d.z, 30.0f));
                float e3 = fexp2(fminf(d.w, 30.0f));
                uint4v pu;
                pu.x = ((unsigned)f2bf(e1) << 16) | (unsigned)f2bf(e0);
                pu.y = ((unsigned)f2bf(e3) << 16) | (unsigned)f2bf(e2);
                pu.z = pu.x; pu.w = pu.y;     // duplicate P for the lo K-slots
                short8 pa = __builtin_bit_cast(short8, pu);
                O[j] = __builtin_amdgcn_mfma_f32_16x16x32_bf16(pa, vh, O[j], 0, 0, 0);
            }
            ah = ah_n; al = al_n; vh = vh_n;
        }
    }

    // ---- write partials ----
    if (lane < 16) {
#pragma unroll
        for (int j = 0; j < 2; j++)
            pm[split * NPX + (pxg * 2 + j) * 16 + lane] = mval[j];
    }
    // O: lane holds channel ch=lane&15, pixels 4*(lane>>4)+reg
    const int ch = lane & 15, rg = lane >> 4;
    if (ch < 4) {
        float* dst = (ch == 0) ? pc0 : (ch == 1) ? pc1 : (ch == 2) ? pc2 : ps;
#pragma unroll
        for (int j = 0; j < 2; j++) {
            int base = split * NPX + (pxg * 2 + j) * 16 + 4 * rg;
            dst[base + 0] = O[j].x;
            dst[base + 1] = O[j].y;
            dst[base + 2] = O[j].z;
            dst[base + 3] = O[j].w;
        }
    }
}

// ---- combine partials + write output ----
__global__ void __launch_bounds__(64) combine(const float* __restrict__ x, const float* __restrict__ t,
                        const float* __restrict__ pm, const float* __restrict__ ps,
                        const float* __restrict__ pc0, const float* __restrict__ pc1,
                        const float* __restrict__ pc2, float* __restrict__ out) {
    int px = blockIdx.x * 64 + threadIdx.x;
    if (px >= NPX) return;
    float M = -1e30f, S = 0.0f, C0 = 0.0f, C1 = 0.0f, C2 = 0.0f;
#pragma unroll 8
    for (int sp = 0; sp < SPLITS; sp++) {
        int o = sp * NPX + px;
        float mi = pm[o];
        float Mn = fmaxf(M, mi);
        float al = fexp2(M - Mn);
        float be = fexp2(mi - Mn);
        S  = S  * al + ps[o]  * be;
        C0 = C0 * al + pc0[o] * be;
        C1 = C1 * al + pc1[o] * be;
        C2 = C2 * al + pc2[o] * be;
        M = Mn;
    }
    float bt2 = t[0];
    float at = sqrtf(1.0f - bt2);
    float invS = 1.0f / fmaxf(S, 1e-37f);
    float ibt = 1.0f / bt2;
    int b = px >> 10, rem = px & 1023, h = rem >> 5, w = rem & 31;
    int xi = b * 3072 + h * 32 + w;
    out[xi]        = (at * C0 * invS - x[xi]) * ibt;
    out[xi + 1024] = (at * C1 * invS - x[xi + 1024]) * ibt;
    out[xi + 2048] = (at * C2 * invS - x[xi + 2048]) * ibt;
}

extern "C" void kernel_launch(void* const* d_in, const int* in_sizes, int n_in,
                              void* d_out, int out_size, void* d_ws, size_t ws_size,
                              hipStream_t stream) {
    const float* x = (const float*)d_in[0];
    const float* patches = (const float*)d_in[1];
    const float* t = (const float*)d_in[2];
    float* out = (float*)d_out;
    float* ws = (float*)d_ws;

    float* gAh = ws;                      // 131072 floats each
    float* gAl = ws + 131072;
    float* gBh = ws + 262144;
    float* gBl = ws + 393216;
    float* gVh = ws + 524288;
    float* pm  = ws + 655360;             // 32*8192 floats each -> total ~7.9 MB
    float* ps  = pm + SPLITS * NPX;
    float* pc0 = ps + SPLITS * NPX;
    float* pc1 = pc0 + SPLITS * NPX;
    float* pc2 = pc1 + SPLITS * NPX;

    hipLaunchKernelGGL(prep, dim3(192), dim3(256), 0, stream,
                       x, patches, t, gAh, gAl, gBh, gBl, gVh);
    hipLaunchKernelGGL(main_mfma, dim3(SPLITS, PXB), dim3(WPB * 64), 0, stream,
                       gAh, gAl, gBh, gBl, gVh, pm, ps, pc0, pc1, pc2);
    hipLaunchKernelGGL(combine, dim3(NPX / 64), dim3(64), 0, stream,
                       x, t, pm, ps, pc0, pc1, pc2, out);
}

// Round 10
// 29.720 us; speedup vs baseline: 1.4618x; 1.3940x over previous
//
#include <hip/hip_runtime.h>
#include <math.h>

typedef __attribute__((ext_vector_type(8))) short short8;
typedef __attribute__((ext_vector_type(4))) float f32x4;
typedef __attribute__((ext_vector_type(4))) unsigned int uint4v;

#define NPX 8192
#define NPATCH 8192
#define SPLITS 32
#define TILES 16             // 16-patch tiles per split (256 patches/split)
#define WPB 8                // waves per block (512 threads)
#define PXB 32               // pixel-blocks: 32 blocks * 8 waves * 32 px = 8192

__device__ __forceinline__ float fexp2(float x) {
#if __has_builtin(__builtin_amdgcn_exp2f)
    return __builtin_amdgcn_exp2f(x);
#else
    return exp2f(x);
#endif
}

__device__ __forceinline__ unsigned short f2bf(float f) {
    unsigned u = __float_as_uint(f);
    u = u + 0x7FFFu + ((u >> 16) & 1u);
    return (unsigned short)(u >> 16);
}
__device__ __forceinline__ float bf2f(unsigned short h) {
    return __uint_as_float(((unsigned)h) << 16);
}
// pack truncated bf16(e1):bf16(e0) in one op
__device__ __forceinline__ unsigned pack_hi16(unsigned u1, unsigned u0) {
#if __has_builtin(__builtin_amdgcn_perm)
    return __builtin_amdgcn_perm(u1, u0, 0x07060302u);
#else
    return (u1 & 0xFFFF0000u) | (u0 >> 16);
#endif
}

// ---- prep: A-fragments (patches, hi/lo, slot27=B2, slot28=1.0/0),
//            B-fragments (pixels, hi/lo, slot27=1.0/0, slot28=-mhat/0),
//            V-fragments (centers+ones: hi in k-elems 0..3, lo in 4..7).
__global__ void __launch_bounds__(256) prep(const float* __restrict__ x,
                          const float* __restrict__ patches,
                          const float* __restrict__ t,
                          float* __restrict__ gAh, float* __restrict__ gAl,
                          float* __restrict__ gBh, float* __restrict__ gBl,
                          float* __restrict__ gVh) {
    int id = blockIdx.x * 256 + threadIdx.x;
    float bt2 = t[0];
    float at = sqrtf(1.0f - bt2);
    const float L2E = 1.4426950408889634f;
    if (id < NPATCH) {
        int p = id;
        const float* src = patches + p * 27;
        float v[27]; float pn = 0.f;
#pragma unroll
        for (int k = 0; k < 27; k++) { v[k] = src[k]; pn += v[k] * v[k]; }
        float A2 = at * L2E / bt2;
        float B2 = -at * at * pn * L2E / (2.0f * bt2);
        float sv[28];
#pragma unroll
        for (int k = 0; k < 27; k++) sv[k] = A2 * v[k];
        sv[27] = B2;
        int j = p >> 4, pi = p & 15;
        short8* Ah8 = (short8*)gAh; short8* Al8 = (short8*)gAl;
#pragma unroll
        for (int c = 0; c < 4; c++) {
            short8 H, L;
#pragma unroll
            for (int i = 0; i < 8; i++) {
                int k = c * 8 + i;
                unsigned short hb = 0, lb = 0;
                if (k < 28) { hb = f2bf(sv[k]); lb = f2bf(sv[k] - bf2f(hb)); }
                else if (k == 28) { hb = 0x3F80; lb = 0; }   // 1.0: multiplies -mhat
                H[i] = (short)hb; L[i] = (short)lb;
            }
            Ah8[j * 64 + c * 16 + pi] = H;
            Al8[j * 64 + c * 16 + pi] = L;
        }
    } else if (id < NPATCH + NPX) {
        int px = id - NPATCH;
        int b = px >> 10, rem = px & 1023, h = rem >> 5, w = rem & 31;
        float xv[28];
        float xn = 0.f;
#pragma unroll
        for (int c3 = 0; c3 < 3; c3++)
#pragma unroll
        for (int dr = 0; dr < 3; dr++)
#pragma unroll
        for (int dc = 0; dc < 3; dc++) {
            int hh = h + dr - 1, ww = w + dc - 1;
            float val = 0.f;
            if ((unsigned)hh < 32u && (unsigned)ww < 32u)
                val = x[b * 3072 + c3 * 1024 + hh * 32 + ww];
            xv[c3 * 9 + dr * 3 + dc] = val;
            xn += val * val;
        }
        xv[27] = 1.0f;
        // analytic logit upper bound (log2 units), window-shifted by -40
        float mraw = L2E * xn / (2.0f * bt2) - 40.0f;
        unsigned short mh = f2bf(mraw);            // mhat = bf2f(mh), exactly representable
        int wv = px >> 4, pi = px & 15;
        short8* Bh8 = (short8*)gBh; short8* Bl8 = (short8*)gBl;
#pragma unroll
        for (int c = 0; c < 4; c++) {
            short8 H, L;
#pragma unroll
            for (int i = 0; i < 8; i++) {
                int k = c * 8 + i;
                unsigned short hb = 0, lb = 0;
                if (k < 28) { hb = f2bf(xv[k]); lb = f2bf(xv[k] - bf2f(hb)); }
                else if (k == 28) { hb = (unsigned short)(mh ^ 0x8000u); lb = 0; } // -mhat
                H[i] = (short)hb; L[i] = (short)lb;
            }
            Bh8[wv * 64 + c * 16 + pi] = H;
            Bl8[wv * 64 + c * 16 + pi] = L;
        }
    } else {
        // V-fragments: elems 0..3 = center hi (patches 4g..4g+3), elems 4..7 = lo.
        // cols 0..2 = channel centers, col 3 = ones (S column). Other cols zero.
        int vid = id - (NPATCH + NPX);          // 0 .. 512*64-1
        int tile = vid >> 6, lane = vid & 63;
        int g = (lane >> 4) & 3, col = lane & 15;
        short8 H;
#pragma unroll
        for (int i = 0; i < 8; i++) {
            unsigned short bb = 0;
            if (col < 4) {
                int ii = i & 3;
                float val;
                if (col == 3) val = 1.0f;       // ones column -> S
                else {
                    int p = tile * 16 + 4 * g + ii;
                    val = patches[p * 27 + (col == 0 ? 4 : col == 1 ? 13 : 22)];
                }
                unsigned short hb = f2bf(val);
                bb = (i < 4) ? hb : f2bf(val - bf2f(hb));   // hi then lo
            }
            H[i] = (short)bb;
        }
        ((short8*)gVh)[vid] = H;
    }
}

// ---- main: single pass — QK logits (-mhat pre-folded), exp2, PV via MFMA ----
__global__ void __launch_bounds__(512) main_mfma(
        const float* __restrict__ gAh, const float* __restrict__ gAl,
        const float* __restrict__ gBh, const float* __restrict__ gBl,
        const float* __restrict__ gVh,
        float* __restrict__ ps,
        float* __restrict__ pc0, float* __restrict__ pc1, float* __restrict__ pc2) {
    __shared__ short8 sAh[TILES * 64];   // 16 KB each, 48 KB total -> 3 blocks/CU
    __shared__ short8 sAl[TILES * 64];
    __shared__ short8 sVh[TILES * 64];
    const int tid = threadIdx.x;
    const int lane = tid & 63, wid = tid >> 6;
    const int split = blockIdx.x, pxb = blockIdx.y;
    const int tb = split * TILES;

    // stage A-hi, A-lo, V fragment records (coalesced float4)
    {
        const float4* s0 = (const float4*)gAh + tb * 64;
        const float4* s1 = (const float4*)gAl + tb * 64;
        const float4* s2 = (const float4*)gVh + tb * 64;
        float4* d0 = (float4*)sAh; float4* d1 = (float4*)sAl; float4* d2 = (float4*)sVh;
#pragma unroll
        for (int i = 0; i < 2; i++) {
            d0[tid + i * 512] = s0[tid + i * 512];
            d1[tid + i * 512] = s1[tid + i * 512];
            d2[tid + i * 512] = s2[tid + i * 512];
        }
    }

    // pixel fragments: 2 groups of 16 pixels per wave (32 px/wave)
    const int pxg = pxb * WPB + wid;             // 0..255
    short8 bh[2], bl[2];
#pragma unroll
    for (int j = 0; j < 2; j++) {
        bh[j] = ((const short8*)gBh)[(pxg * 2 + j) * 64 + lane];
        bl[j] = ((const short8*)gBl)[(pxg * 2 + j) * 64 + lane];
    }
    __syncthreads();

    const f32x4 z4 = {0.f, 0.f, 0.f, 0.f};
    f32x4 O[2] = {z4, z4};
#pragma unroll
    for (int tt = 0; tt < TILES; tt++) {
        short8 ah = sAh[tt * 64 + lane];
        short8 al = sAl[tt * 64 + lane];
        short8 vh = sVh[tt * 64 + lane];
#pragma unroll
        for (int j = 0; j < 2; j++) {
            f32x4 d = __builtin_amdgcn_mfma_f32_16x16x32_bf16(al, bh[j], z4, 0, 0, 0);
            d = __builtin_amdgcn_mfma_f32_16x16x32_bf16(ah, bl[j], d, 0, 0, 0);
            d = __builtin_amdgcn_mfma_f32_16x16x32_bf16(ah, bh[j], d, 0, 0, 0);
            // d <= 40 by the analytic bound -> e <= 2^40, no clamp needed
            unsigned u0 = __float_as_uint(fexp2(d.x));
            unsigned u1 = __float_as_uint(fexp2(d.y));
            unsigned u2 = __float_as_uint(fexp2(d.z));
            unsigned u3 = __float_as_uint(fexp2(d.w));
            uint4v pu;
            pu.x = pack_hi16(u1, u0);
            pu.y = pack_hi16(u3, u2);
            pu.z = pu.x; pu.w = pu.y;     // duplicate P for the V-lo K-slots
            short8 pa = __builtin_bit_cast(short8, pu);
            O[j] = __builtin_amdgcn_mfma_f32_16x16x32_bf16(pa, vh, O[j], 0, 0, 0);
        }
    }

    // ---- write partials: lane holds channel ch=lane&15, pixels 4*(lane>>4)+reg ----
    const int ch = lane & 15, rg = lane >> 4;
    if (ch < 4) {
        float* dst = (ch == 0) ? pc0 : (ch == 1) ? pc1 : (ch == 2) ? pc2 : ps;
#pragma unroll
        for (int j = 0; j < 2; j++) {
            int base = split * NPX + (pxg * 2 + j) * 16 + 4 * rg;
            dst[base + 0] = O[j].x;
            dst[base + 1] = O[j].y;
            dst[base + 2] = O[j].z;
            dst[base + 3] = O[j].w;
        }
    }
}

// ---- combine: pure sum over splits (shared mhat cancels in C/S) ----
__global__ void __launch_bounds__(64) combine(const float* __restrict__ x, const float* __restrict__ t,
                        const float* __restrict__ ps,
                        const float* __restrict__ pc0, const float* __restrict__ pc1,
                        const float* __restrict__ pc2, float* __restrict__ out) {
    int px = blockIdx.x * 64 + threadIdx.x;
    if (px >= NPX) return;
    float S = 0.0f, C0 = 0.0f, C1 = 0.0f, C2 = 0.0f;
#pragma unroll 8
    for (int sp = 0; sp < SPLITS; sp++) {
        int o = sp * NPX + px;
        S  += ps[o];
        C0 += pc0[o];
        C1 += pc1[o];
        C2 += pc2[o];
    }
    float bt2 = t[0];
    float at = sqrtf(1.0f - bt2);
    float invS = 1.0f / fmaxf(S, 1e-37f);
    float ibt = 1.0f / bt2;
    int b = px >> 10, rem = px & 1023, h = rem >> 5, w = rem & 31;
    int xi = b * 3072 + h * 32 + w;
    out[xi]        = (at * C0 * invS - x[xi]) * ibt;
    out[xi + 1024] = (at * C1 * invS - x[xi + 1024]) * ibt;
    out[xi + 2048] = (at * C2 * invS - x[xi + 2048]) * ibt;
}

extern "C" void kernel_launch(void* const* d_in, const int* in_sizes, int n_in,
                              void* d_out, int out_size, void* d_ws, size_t ws_size,
                              hipStream_t stream) {
    const float* x = (const float*)d_in[0];
    const float* patches = (const float*)d_in[1];
    const float* t = (const float*)d_in[2];
    float* out = (float*)d_out;
    float* ws = (float*)d_ws;

    float* gAh = ws;                      // 131072 floats each
    float* gAl = ws + 131072;
    float* gBh = ws + 262144;
    float* gBl = ws + 393216;
    float* gVh = ws + 524288;
    float* ps  = ws + 655360;             // 32*8192 floats each -> total 6.5 MB
    float* pc0 = ps + SPLITS * NPX;
    float* pc1 = pc0 + SPLITS * NPX;
    float* pc2 = pc1 + SPLITS * NPX;

    hipLaunchKernelGGL(prep, dim3(192), dim3(256), 0, stream,
                       x, patches, t, gAh, gAl, gBh, gBl, gVh);
    hipLaunchKernelGGL(main_mfma, dim3(SPLITS, PXB), dim3(WPB * 64), 0, stream,
                       gAh, gAl, gBh, gBl, gVh, ps, pc0, pc1, pc2);
    hipLaunchKernelGGL(combine, dim3(NPX / 64), dim3(64), 0, stream,
                       x, t, ps, pc0, pc1, pc2, out);
}